// Round 3
// baseline (790.941 us; speedup 1.0000x reference)
//
#include <hip/hip_runtime.h>

#define D 128
#define RPB 64        // rows per bin (power of 2)
#define RPB_SHIFT 6
#define EPT 8         // edges per thread in histogram/sort
#define CHUNK (256 * EPT)  // 2048 edges per chunk-block
#define ACC_STRIDE 136     // skewed LDS accumulator row stride (words)

typedef __attribute__((ext_vector_type(8))) short short8;
typedef __attribute__((ext_vector_type(4))) float floatx4;
typedef unsigned int uint;
typedef unsigned short ushort;

__device__ inline short f2bf(float f) {
  unsigned u = __float_as_uint(f);
  u += 0x7FFF + ((u >> 16) & 1);  // RNE
  return (short)(u >> 16);
}

// --- Kernel A. Blocks [0, gemm_blocks): MFMA GEMM support = bf16(x @ W)
// (r0 code verbatim). Blocks [gemm_blocks, +nc): per-chunk row-bin histogram
// (LDS atomics only -> counts[bin][chunk]). Co-scheduled (m114).
// r13 THEORY: r0/r12 proved the 800K device-scope atomicAdds are the K1
// limiter (~7/cy device-wide, locality-insensitive: physical-XCD binding
// didn't help, workgroup scope regressed). Fix = counting sort: histogram +
// prefix sums + deterministic scatter. Zero global atomics anywhere.
__global__ __launch_bounds__(256) void gemm_hist_kernel(
    const float* __restrict__ x, const float* __restrict__ w,
    ushort* __restrict__ support, int n_nodes, int gemm_blocks,
    const int* __restrict__ adj_row, int* __restrict__ counts,
    int n_edges, int nb, int nc) {
  __shared__ short sWA[2 * 8 * 64 * 8];  // 16 KB (GEMM W tiles)
  __shared__ int hist[1024];             // histogram branch (nb <= 1024)
  const int tid = threadIdx.x;

  if ((int)blockIdx.x < gemm_blocks) {
    // ---------------- GEMM branch (r0 verbatim) ----------------
    const int wid = tid >> 6;
    const int lane = tid & 63;
    const int quad = lane >> 4;
    const int node = blockIdx.x * 64 + wid * 16 + (lane & 15);
    const bool ok = (node < n_nodes);

    floatx4 acc[8];
#pragma unroll
    for (int mt = 0; mt < 8; ++mt) acc[mt] = (floatx4){0.f, 0.f, 0.f, 0.f};

#pragma unroll
    for (int kt2 = 0; kt2 < 4; kt2 += 2) {
      if (kt2) __syncthreads();  // drain readers before restaging
      // Conflict-free staging (r8: 6M -> 0 conflicts).
      for (int s = tid; s < 1024; s += 256) {
        int ktmt = s >> 6, ls = s & 63;
        int kt = kt2 + (ktmt >> 3);
        int kb = kt * 32 + (ls >> 4) * 8;
        int m = (ktmt & 7) * 16 + (ls & 15);
        short8 frag;
#pragma unroll
        for (int j = 0; j < 8; ++j) frag[j] = f2bf(w[(kb + j) * D + m]);
        *(short8*)&sWA[s * 8] = frag;
      }
      __syncthreads();

#pragma unroll
      for (int ktoff = 0; ktoff < 2; ++ktoff) {
        const int kt = kt2 + ktoff;
        short8 bfr = (short8){0, 0, 0, 0, 0, 0, 0, 0};
        if (ok) {
          const float4 v0 = *(const float4*)&x[(size_t)node * D + kt * 32 + quad * 8];
          const float4 v1 = *(const float4*)&x[(size_t)node * D + kt * 32 + quad * 8 + 4];
          bfr = (short8){f2bf(v0.x), f2bf(v0.y), f2bf(v0.z), f2bf(v0.w),
                         f2bf(v1.x), f2bf(v1.y), f2bf(v1.z), f2bf(v1.w)};
        }
#pragma unroll
        for (int mt = 0; mt < 8; ++mt) {
          short8 a = *(const short8*)&sWA[((ktoff * 8 + mt) * 64 + lane) * 8];
          acc[mt] = __builtin_amdgcn_mfma_f32_16x16x32_bf16(a, bfr, acc[mt], 0, 0, 0);
        }
      }
    }

    if (ok) {
#pragma unroll
      for (int mt = 0; mt < 8; ++mt) {
        uint lo = ((uint)(ushort)f2bf(acc[mt][1]) << 16) | (ushort)f2bf(acc[mt][0]);
        uint hi = ((uint)(ushort)f2bf(acc[mt][3]) << 16) | (ushort)f2bf(acc[mt][2]);
        *(uint2*)&support[(size_t)node * D + mt * 16 + quad * 4] = make_uint2(lo, hi);
      }
    }
  } else {
    // ---------------- histogram branch ----------------
    const int c = blockIdx.x - gemm_blocks;
    for (int i = tid; i < nb; i += 256) hist[i] = 0;
    __syncthreads();
    const int base = c * CHUNK + tid * EPT;
    if (base + EPT <= n_edges) {
      int4 r0 = *(const int4*)&adj_row[base];
      int4 r1 = *(const int4*)&adj_row[base + 4];
      int rr[EPT] = {r0.x, r0.y, r0.z, r0.w, r1.x, r1.y, r1.z, r1.w};
#pragma unroll
      for (int u = 0; u < EPT; ++u) atomicAdd(&hist[rr[u] >> RPB_SHIFT], 1);
    } else {
      for (int u = 0; u < EPT; ++u) {
        int e = base + u;
        if (e < n_edges) atomicAdd(&hist[adj_row[e] >> RPB_SHIFT], 1);
      }
    }
    __syncthreads();
    for (int b = tid; b < nb; b += 256)
      counts[(size_t)b * nc + c] = hist[b];
  }
}

// --- Per-bin exclusive scan over chunks (in place) + bin totals.
// Block b scans counts[b*nc .. b*nc+nc). nc <= 512.
__global__ __launch_bounds__(256) void scan_chunks_kernel(int* __restrict__ counts,
                                                          int* __restrict__ tot,
                                                          int nb, int nc) {
  __shared__ int buf[512];
  const int b = blockIdx.x;
  const int t = threadIdx.x;
  int v0 = (t < nc) ? counts[(size_t)b * nc + t] : 0;
  int v1 = (256 + t < nc) ? counts[(size_t)b * nc + 256 + t] : 0;
  buf[t] = v0;
  buf[256 + t] = v1;
  __syncthreads();
  for (int off = 1; off < 512; off <<= 1) {
    int a0 = buf[t], a1 = buf[256 + t];
    int d0 = (t >= off) ? buf[t - off] : 0;
    int d1 = (256 + t >= off) ? buf[256 + t - off] : 0;
    __syncthreads();
    buf[t] = a0 + d0;
    buf[256 + t] = a1 + d1;
    __syncthreads();
  }
  if (t < nc) counts[(size_t)b * nc + t] = buf[t] - v0;                // exclusive
  if (256 + t < nc) counts[(size_t)b * nc + 256 + t] = buf[256 + t] - v1;
  if (t == 0) tot[b] = buf[511];
}

// --- Exclusive scan over bin totals -> binStart[0..nb], binStart[nb]=n_edges.
// Single block; nb <= 1024.
__global__ __launch_bounds__(256) void scan_bins_kernel(const int* __restrict__ tot,
                                                        int* __restrict__ binStart,
                                                        int nb) {
  __shared__ int buf[1024];
  const int t = threadIdx.x;
  for (int i = t; i < 1024; i += 256) buf[i] = (i < nb) ? tot[i] : 0;
  __syncthreads();
  for (int off = 1; off < 1024; off <<= 1) {
    int a[4], d[4];
#pragma unroll
    for (int k = 0; k < 4; ++k) {
      int i = t + 256 * k;
      a[k] = buf[i];
      d[k] = (i >= off) ? buf[i - off] : 0;
    }
    __syncthreads();
#pragma unroll
    for (int k = 0; k < 4; ++k) buf[t + 256 * k] = a[k] + d[k];
    __syncthreads();
  }
  for (int i = t; i < nb; i += 256) binStart[i] = buf[i] - tot[i];  // exclusive
  if (t == 0) binStart[nb] = buf[1023];
}

// --- Deterministic scatter into bin-sorted order. Block = chunk c. Slot =
// binStart[b] + rel[b][c] + (LDS running offset). Disjoint regions by
// construction -> plain stores, no global atomics. Entry: {rrel<<16|col, f32 val}.
__global__ __launch_bounds__(256) void sort_scatter_kernel(
    const int* __restrict__ adj_row, const int* __restrict__ adj_col,
    const float* __restrict__ adj_val, const int* __restrict__ rel,
    const int* __restrict__ binStart, uint2* __restrict__ sorted,
    int n_edges, int nb, int nc) {
  __shared__ int loff[1024];
  const int c = blockIdx.x;
  const int t = threadIdx.x;
  for (int i = t; i < nb; i += 256)
    loff[i] = binStart[i] + rel[(size_t)i * nc + c];
  __syncthreads();

  const int base = c * CHUNK + t * EPT;
  if (base + EPT <= n_edges) {
    int4 r0 = *(const int4*)&adj_row[base];
    int4 r1 = *(const int4*)&adj_row[base + 4];
    int4 c0 = *(const int4*)&adj_col[base];
    int4 c1 = *(const int4*)&adj_col[base + 4];
    float4 v0 = *(const float4*)&adj_val[base];
    float4 v1 = *(const float4*)&adj_val[base + 4];
    int rr[EPT] = {r0.x, r0.y, r0.z, r0.w, r1.x, r1.y, r1.z, r1.w};
    int cc[EPT] = {c0.x, c0.y, c0.z, c0.w, c1.x, c1.y, c1.z, c1.w};
    float vv[EPT] = {v0.x, v0.y, v0.z, v0.w, v1.x, v1.y, v1.z, v1.w};
#pragma unroll
    for (int u = 0; u < EPT; ++u) {
      int r = rr[u];
      int pos = atomicAdd(&loff[r >> RPB_SHIFT], 1);  // LDS atomic
      sorted[pos] = make_uint2(((uint)(r & (RPB - 1)) << 16) | (uint)cc[u],
                               __float_as_uint(vv[u]));
    }
  } else {
    for (int u = 0; u < EPT; ++u) {
      int e = base + u;
      if (e >= n_edges) break;
      int r = adj_row[e];
      int pos = atomicAdd(&loff[r >> RPB_SHIFT], 1);
      sorted[pos] = make_uint2(((uint)(r & (RPB - 1)) << 16) | (uint)adj_col[e],
                               __float_as_uint(adj_val[e]));
    }
  }
}

// --- Per-bin SpMM: block = bin (64 rows). LDS f32 accumulator with hl-skew
// (word = rrel*136 + hl*8 + j + (hl>>2): 16 lanes of a group hit 16 distinct
// banks; group offset 8*rrel spreads groups -> ~2-way = free, m136). 16 groups
// of 16 lanes; group takes one edge: contiguous uint2 read (broadcast), 256B
// support gather (uint4/lane, same as old K2), 8x ds_add_f32. Coalesced
// out = acc + bias write.
__global__ __launch_bounds__(256) void bin_spmm_kernel(
    const uint2* __restrict__ sorted, const int* __restrict__ binStart,
    const uint* __restrict__ sup, const float* __restrict__ bias,
    float* __restrict__ out, int n_nodes, int nb) {
  __shared__ float acc[RPB * ACC_STRIDE];  // 34816 B
  const int b = blockIdx.x;
  const int t = threadIdx.x;
  for (int i = t; i < RPB * ACC_STRIDE; i += 256) acc[i] = 0.f;
  __syncthreads();

  const int s0 = binStart[b];
  const int s1 = binStart[b + 1];
  const int grp = t >> 4;   // 16 groups
  const int hl = t & 15;    // lane within group
  const int skew = hl * 8 + (hl >> 2);

  for (int i = s0 + grp; i < s1; i += 16) {
    uint2 e = sorted[i];
    int rrel = (int)(e.x >> 16);
    uint col = e.x & 0xFFFFu;
    float v = __uint_as_float(e.y);
    uint4 s = *(const uint4*)&sup[(size_t)col * 64 + hl * 4];
    float* dst = &acc[rrel * ACC_STRIDE + skew];
    atomicAdd(&dst[0], v * __uint_as_float(s.x << 16));
    atomicAdd(&dst[1], v * __uint_as_float(s.x & 0xffff0000u));
    atomicAdd(&dst[2], v * __uint_as_float(s.y << 16));
    atomicAdd(&dst[3], v * __uint_as_float(s.y & 0xffff0000u));
    atomicAdd(&dst[4], v * __uint_as_float(s.z << 16));
    atomicAdd(&dst[5], v * __uint_as_float(s.z & 0xffff0000u));
    atomicAdd(&dst[6], v * __uint_as_float(s.w << 16));
    atomicAdd(&dst[7], v * __uint_as_float(s.w & 0xffff0000u));
  }
  __syncthreads();

  // out write: thread t covers row b*64 + (t>>2), features [(t&3)*32, +32)
  const int rr = t >> 2;
  const int row = b * RPB + rr;
  const int seg = (t & 3) * 32;
  if (row < n_nodes) {
#pragma unroll
    for (int j = 0; j < 32; j += 4) {
      int d = seg + j;
      float4 bv = *(const float4*)&bias[d];
      // inverse of store mapping: word(rr,d) = rr*136 + d + (d>>5)... d here is
      // feature index; store used hl=d>>3, j=d&7 -> offset d + ((d>>3)>>2) = d + (d>>5)
      float a0 = acc[rr * ACC_STRIDE + (d + 0) + ((d + 0) >> 5)];
      float a1 = acc[rr * ACC_STRIDE + (d + 1) + ((d + 1) >> 5)];
      float a2 = acc[rr * ACC_STRIDE + (d + 2) + ((d + 2) >> 5)];
      float a3 = acc[rr * ACC_STRIDE + (d + 3) + ((d + 3) >> 5)];
      *(float4*)&out[(size_t)row * D + d] =
          make_float4(a0 + bv.x, a1 + bv.y, a2 + bv.z, a3 + bv.w);
    }
  }
}

extern "C" void kernel_launch(void* const* d_in, const int* in_sizes, int n_in,
                              void* d_out, int out_size, void* d_ws, size_t ws_size,
                              hipStream_t stream) {
  const float* x       = (const float*)d_in[0];
  const float* w       = (const float*)d_in[1];
  const float* bias    = (const float*)d_in[2];
  const int*   adj_row = (const int*)d_in[3];
  const int*   adj_col = (const int*)d_in[4];
  const float* adj_val = (const float*)d_in[5];

  const int n_nodes = in_sizes[0] / D;   // 50000
  const int n_edges = in_sizes[3];       // 800000
  float* out = (float*)d_out;

  const int nb = (n_nodes + RPB - 1) / RPB;        // 782  (<=1024)
  const int nc = (n_edges + CHUNK - 1) / CHUNK;    // 391  (<=512)
  const int gemm_blocks = (n_nodes + 63) / 64;     // 782

  // Workspace layout (16B-aligned). All buffers fully rewritten each
  // iteration -> NO memset needed (poison-safe).
  char* ws = (char*)d_ws;
  ushort* support  = (ushort*)ws; ws += ((size_t)n_nodes * D * 2 + 15) & ~15ull;  // 12.8 MB
  int*    counts   = (int*)ws;    ws += ((size_t)nb * nc * 4 + 15) & ~15ull;      // 1.22 MB
  int*    tot      = (int*)ws;    ws += ((size_t)nb * 4 + 15) & ~15ull;           // 3.1 KB
  int*    binStart = (int*)ws;    ws += ((size_t)(nb + 1) * 4 + 15) & ~15ull;     // 3.1 KB
  uint2*  sorted   = (uint2*)ws;  ws += (size_t)n_edges * 8;                      // 6.4 MB

  // 1) GEMM (782 blocks) || per-chunk histogram (391 blocks)
  gemm_hist_kernel<<<gemm_blocks + nc, 256, 0, stream>>>(
      x, w, support, n_nodes, gemm_blocks, adj_row, counts, n_edges, nb, nc);

  // 2) per-bin exclusive scan over chunks (in place) + totals
  scan_chunks_kernel<<<nb, 256, 0, stream>>>(counts, tot, nb, nc);

  // 3) exclusive scan over bins
  scan_bins_kernel<<<1, 256, 0, stream>>>(tot, binStart, nb);

  // 4) deterministic bin-sort of edges (no global atomics)
  sort_scatter_kernel<<<nc, 256, 0, stream>>>(adj_row, adj_col, adj_val,
                                              counts, binStart, sorted,
                                              n_edges, nb, nc);

  // 5) per-bin SpMM: out = bias + A @ support
  bin_spmm_kernel<<<nb, 256, 0, stream>>>(sorted, binStart, (const uint*)support,
                                          bias, out, n_nodes, nb);
}

// Round 4
// 146.435 us; speedup vs baseline: 5.4013x; 5.4013x over previous
//
#include <hip/hip_runtime.h>

#define D 128
#define RPB 64        // rows per bin (power of 2)
#define RPB_SHIFT 6
#define EPT 8         // edges per thread in histogram/sort
#define CHUNK (256 * EPT)  // 2048 edges per chunk-block
#define PASS_EDGES 2048    // edges per bin_spmm pass (bin avg 1023, max ~1200)

typedef __attribute__((ext_vector_type(8))) short short8;
typedef __attribute__((ext_vector_type(4))) float floatx4;
typedef unsigned int uint;
typedef unsigned short ushort;

__device__ inline short f2bf(float f) {
  unsigned u = __float_as_uint(f);
  u += 0x7FFF + ((u >> 16) & 1);  // RNE
  return (short)(u >> 16);
}

// --- Kernel A. Blocks [0, gemm_blocks): MFMA GEMM support = bf16(x @ W)
// (r0 code verbatim). Blocks [gemm_blocks, +nc): per-chunk row-bin histogram
// (LDS int atomics only -> counts[bin][chunk]). Co-scheduled (m114).
// r13: counting sort replaced 800K device-scope atomics (proven limiter).
__global__ __launch_bounds__(256) void gemm_hist_kernel(
    const float* __restrict__ x, const float* __restrict__ w,
    ushort* __restrict__ support, int n_nodes, int gemm_blocks,
    const int* __restrict__ adj_row, int* __restrict__ counts,
    int n_edges, int nb, int nc) {
  __shared__ short sWA[2 * 8 * 64 * 8];  // 16 KB (GEMM W tiles)
  __shared__ int hist[1024];             // histogram branch (nb <= 1024)
  const int tid = threadIdx.x;

  if ((int)blockIdx.x < gemm_blocks) {
    // ---------------- GEMM branch (r0 verbatim) ----------------
    const int wid = tid >> 6;
    const int lane = tid & 63;
    const int quad = lane >> 4;
    const int node = blockIdx.x * 64 + wid * 16 + (lane & 15);
    const bool ok = (node < n_nodes);

    floatx4 acc[8];
#pragma unroll
    for (int mt = 0; mt < 8; ++mt) acc[mt] = (floatx4){0.f, 0.f, 0.f, 0.f};

#pragma unroll
    for (int kt2 = 0; kt2 < 4; kt2 += 2) {
      if (kt2) __syncthreads();  // drain readers before restaging
      // Conflict-free staging (r8: 6M -> 0 conflicts).
      for (int s = tid; s < 1024; s += 256) {
        int ktmt = s >> 6, ls = s & 63;
        int kt = kt2 + (ktmt >> 3);
        int kb = kt * 32 + (ls >> 4) * 8;
        int m = (ktmt & 7) * 16 + (ls & 15);
        short8 frag;
#pragma unroll
        for (int j = 0; j < 8; ++j) frag[j] = f2bf(w[(kb + j) * D + m]);
        *(short8*)&sWA[s * 8] = frag;
      }
      __syncthreads();

#pragma unroll
      for (int ktoff = 0; ktoff < 2; ++ktoff) {
        const int kt = kt2 + ktoff;
        short8 bfr = (short8){0, 0, 0, 0, 0, 0, 0, 0};
        if (ok) {
          const float4 v0 = *(const float4*)&x[(size_t)node * D + kt * 32 + quad * 8];
          const float4 v1 = *(const float4*)&x[(size_t)node * D + kt * 32 + quad * 8 + 4];
          bfr = (short8){f2bf(v0.x), f2bf(v0.y), f2bf(v0.z), f2bf(v0.w),
                         f2bf(v1.x), f2bf(v1.y), f2bf(v1.z), f2bf(v1.w)};
        }
#pragma unroll
        for (int mt = 0; mt < 8; ++mt) {
          short8 a = *(const short8*)&sWA[((ktoff * 8 + mt) * 64 + lane) * 8];
          acc[mt] = __builtin_amdgcn_mfma_f32_16x16x32_bf16(a, bfr, acc[mt], 0, 0, 0);
        }
      }
    }

    if (ok) {
#pragma unroll
      for (int mt = 0; mt < 8; ++mt) {
        uint lo = ((uint)(ushort)f2bf(acc[mt][1]) << 16) | (ushort)f2bf(acc[mt][0]);
        uint hi = ((uint)(ushort)f2bf(acc[mt][3]) << 16) | (ushort)f2bf(acc[mt][2]);
        *(uint2*)&support[(size_t)node * D + mt * 16 + quad * 4] = make_uint2(lo, hi);
      }
    }
  } else {
    // ---------------- histogram branch ----------------
    const int c = blockIdx.x - gemm_blocks;
    for (int i = tid; i < nb; i += 256) hist[i] = 0;
    __syncthreads();
    const int base = c * CHUNK + tid * EPT;
    if (base + EPT <= n_edges) {
      int4 r0 = *(const int4*)&adj_row[base];
      int4 r1 = *(const int4*)&adj_row[base + 4];
      int rr[EPT] = {r0.x, r0.y, r0.z, r0.w, r1.x, r1.y, r1.z, r1.w};
#pragma unroll
      for (int u = 0; u < EPT; ++u) atomicAdd(&hist[rr[u] >> RPB_SHIFT], 1);
    } else {
      for (int u = 0; u < EPT; ++u) {
        int e = base + u;
        if (e < n_edges) atomicAdd(&hist[adj_row[e] >> RPB_SHIFT], 1);
      }
    }
    __syncthreads();
    for (int b = tid; b < nb; b += 256)
      counts[(size_t)b * nc + c] = hist[b];
  }
}

// --- Per-bin exclusive scan over chunks (in place) + bin totals.
__global__ __launch_bounds__(256) void scan_chunks_kernel(int* __restrict__ counts,
                                                          int* __restrict__ tot,
                                                          int nb, int nc) {
  __shared__ int buf[512];
  const int b = blockIdx.x;
  const int t = threadIdx.x;
  int v0 = (t < nc) ? counts[(size_t)b * nc + t] : 0;
  int v1 = (256 + t < nc) ? counts[(size_t)b * nc + 256 + t] : 0;
  buf[t] = v0;
  buf[256 + t] = v1;
  __syncthreads();
  for (int off = 1; off < 512; off <<= 1) {
    int a0 = buf[t], a1 = buf[256 + t];
    int d0 = (t >= off) ? buf[t - off] : 0;
    int d1 = (256 + t >= off) ? buf[256 + t - off] : 0;
    __syncthreads();
    buf[t] = a0 + d0;
    buf[256 + t] = a1 + d1;
    __syncthreads();
  }
  if (t < nc) counts[(size_t)b * nc + t] = buf[t] - v0;                // exclusive
  if (256 + t < nc) counts[(size_t)b * nc + 256 + t] = buf[256 + t] - v1;
  if (t == 0) tot[b] = buf[511];
}

// --- Exclusive scan over bin totals -> binStart[0..nb].
__global__ __launch_bounds__(256) void scan_bins_kernel(const int* __restrict__ tot,
                                                        int* __restrict__ binStart,
                                                        int nb) {
  __shared__ int buf[1024];
  const int t = threadIdx.x;
  for (int i = t; i < 1024; i += 256) buf[i] = (i < nb) ? tot[i] : 0;
  __syncthreads();
  for (int off = 1; off < 1024; off <<= 1) {
    int a[4], d[4];
#pragma unroll
    for (int k = 0; k < 4; ++k) {
      int i = t + 256 * k;
      a[k] = buf[i];
      d[k] = (i >= off) ? buf[i - off] : 0;
    }
    __syncthreads();
#pragma unroll
    for (int k = 0; k < 4; ++k) buf[t + 256 * k] = a[k] + d[k];
    __syncthreads();
  }
  for (int i = t; i < nb; i += 256) binStart[i] = buf[i] - tot[i];  // exclusive
  if (t == 0) binStart[nb] = buf[1023];
}

// --- Deterministic scatter into bin-sorted order (int LDS atomics only).
__global__ __launch_bounds__(256) void sort_scatter_kernel(
    const int* __restrict__ adj_row, const int* __restrict__ adj_col,
    const float* __restrict__ adj_val, const int* __restrict__ rel,
    const int* __restrict__ binStart, uint2* __restrict__ sorted,
    int n_edges, int nb, int nc) {
  __shared__ int loff[1024];
  const int c = blockIdx.x;
  const int t = threadIdx.x;
  for (int i = t; i < nb; i += 256)
    loff[i] = binStart[i] + rel[(size_t)i * nc + c];
  __syncthreads();

  const int base = c * CHUNK + t * EPT;
  if (base + EPT <= n_edges) {
    int4 r0 = *(const int4*)&adj_row[base];
    int4 r1 = *(const int4*)&adj_row[base + 4];
    int4 c0 = *(const int4*)&adj_col[base];
    int4 c1 = *(const int4*)&adj_col[base + 4];
    float4 v0 = *(const float4*)&adj_val[base];
    float4 v1 = *(const float4*)&adj_val[base + 4];
    int rr[EPT] = {r0.x, r0.y, r0.z, r0.w, r1.x, r1.y, r1.z, r1.w};
    int cc[EPT] = {c0.x, c0.y, c0.z, c0.w, c1.x, c1.y, c1.z, c1.w};
    float vv[EPT] = {v0.x, v0.y, v0.z, v0.w, v1.x, v1.y, v1.z, v1.w};
#pragma unroll
    for (int u = 0; u < EPT; ++u) {
      int r = rr[u];
      int pos = atomicAdd(&loff[r >> RPB_SHIFT], 1);  // int LDS atomic (native)
      sorted[pos] = make_uint2(((uint)(r & (RPB - 1)) << 16) | (uint)cc[u],
                               __float_as_uint(vv[u]));
    }
  } else {
    for (int u = 0; u < EPT; ++u) {
      int e = base + u;
      if (e >= n_edges) break;
      int r = adj_row[e];
      int pos = atomicAdd(&loff[r >> RPB_SHIFT], 1);
      sorted[pos] = make_uint2(((uint)(r & (RPB - 1)) << 16) | (uint)adj_col[e],
                               __float_as_uint(adj_val[e]));
    }
  }
}

// --- Per-bin SpMM v2 (r14). r13's f32 LDS atomicAdd = CAS retry loop under
// 16-group same-row contention (685us, VALUBusy 1.2%). v2: in-LDS counting
// sort by row (int ds_add_rtn only), then r0's proven ELL-consumer: 16 lanes
// per row walk the row segment together (LDS broadcast), lane owns 8 features,
// REGISTER accumulation. Zero f32 atomics.
__global__ __launch_bounds__(256) void bin_spmm_kernel(
    const uint2* __restrict__ sorted, const int* __restrict__ binStart,
    const uint* __restrict__ sup, const float* __restrict__ bias,
    float* __restrict__ out, int n_nodes) {
  __shared__ uint2 ebuf[PASS_EDGES];   // 16 KB row-sorted edges
  __shared__ int rowStart[RPB + 1];
  __shared__ int cursor[RPB];          // hist, then running scatter cursor
  const int b = blockIdx.x;
  const int t = threadIdx.x;
  const int wid = t >> 6;
  const int lane = t & 63;
  const int qtr = lane >> 4;
  const int hl = lane & 15;

  const int s0 = binStart[b], s1 = binStart[b + 1];

  float acc[4][8];
#pragma unroll
  for (int it = 0; it < 4; ++it)
#pragma unroll
    for (int k = 0; k < 8; ++k) acc[it][k] = 0.f;

  for (int p0 = s0; p0 < s1; p0 += PASS_EDGES) {  // single pass in practice
    const int cntp = min(PASS_EDGES, s1 - p0);
    __syncthreads();                 // previous pass fully consumed
    if (t < RPB) cursor[t] = 0;
    __syncthreads();

    // Phase 1: load up to 8 edges into registers + row histogram (int atomics)
    uint2 er[8];
    int rr[8];
    const int base = p0 + t * EPT;
#pragma unroll
    for (int u = 0; u < EPT; ++u) {
      if (t * EPT + u < cntp) {
        er[u] = sorted[base + u];
        rr[u] = (int)(er[u].x >> 16);
        atomicAdd(&cursor[rr[u]], 1);
      } else {
        er[u] = make_uint2(0, 0);
        rr[u] = -1;
      }
    }
    __syncthreads();

    // Phase 2: wave 0 scans the 64 row counts (exclusive)
    if (wid == 0) {
      int v = cursor[lane];
      int inc = v;
#pragma unroll
      for (int off = 1; off < 64; off <<= 1) {
        int u = __shfl_up(inc, off);
        if (lane >= off) inc += u;
      }
      rowStart[lane] = inc - v;
      if (lane == 63) rowStart[RPB] = inc;
    }
    __syncthreads();
    if (t < RPB) cursor[t] = rowStart[t];
    __syncthreads();

    // Phase 3: scatter edges into row-sorted LDS buffer
#pragma unroll
    for (int u = 0; u < EPT; ++u) {
      if (rr[u] >= 0) {
        int pos = atomicAdd(&cursor[rr[u]], 1);
        ebuf[pos] = make_uint2(er[u].x & 0xFFFFu, er[u].y);
      }
    }
    __syncthreads();

    // Phase 4: consume. 4 iters x 4 waves x 4 quarters = 64 rows. All 16
    // lanes of a quarter walk the row's segment together (LDS broadcast read);
    // lane hl owns features [hl*8, hl*8+8). Register accumulation.
#pragma unroll
    for (int it = 0; it < 4; ++it) {
      const int rid = it * 16 + wid * 4 + qtr;
      const int js = rowStart[rid], je = rowStart[rid + 1];
      int j = js;
      for (; j + 4 <= je; j += 4) {   // unroll 4: 4 gathers in flight
        uint2 e0 = ebuf[j], e1 = ebuf[j + 1], e2 = ebuf[j + 2], e3 = ebuf[j + 3];
        uint4 sv0 = *(const uint4*)&sup[(size_t)e0.x * 64 + hl * 4];
        uint4 sv1 = *(const uint4*)&sup[(size_t)e1.x * 64 + hl * 4];
        uint4 sv2 = *(const uint4*)&sup[(size_t)e2.x * 64 + hl * 4];
        uint4 sv3 = *(const uint4*)&sup[(size_t)e3.x * 64 + hl * 4];
        float v0 = __uint_as_float(e0.y), v1 = __uint_as_float(e1.y);
        float v2 = __uint_as_float(e2.y), v3 = __uint_as_float(e3.y);
        acc[it][0] = fmaf(v0, __uint_as_float(sv0.x << 16), acc[it][0]);
        acc[it][1] = fmaf(v0, __uint_as_float(sv0.x & 0xffff0000u), acc[it][1]);
        acc[it][2] = fmaf(v0, __uint_as_float(sv0.y << 16), acc[it][2]);
        acc[it][3] = fmaf(v0, __uint_as_float(sv0.y & 0xffff0000u), acc[it][3]);
        acc[it][4] = fmaf(v0, __uint_as_float(sv0.z << 16), acc[it][4]);
        acc[it][5] = fmaf(v0, __uint_as_float(sv0.z & 0xffff0000u), acc[it][5]);
        acc[it][6] = fmaf(v0, __uint_as_float(sv0.w << 16), acc[it][6]);
        acc[it][7] = fmaf(v0, __uint_as_float(sv0.w & 0xffff0000u), acc[it][7]);
        acc[it][0] = fmaf(v1, __uint_as_float(sv1.x << 16), acc[it][0]);
        acc[it][1] = fmaf(v1, __uint_as_float(sv1.x & 0xffff0000u), acc[it][1]);
        acc[it][2] = fmaf(v1, __uint_as_float(sv1.y << 16), acc[it][2]);
        acc[it][3] = fmaf(v1, __uint_as_float(sv1.y & 0xffff0000u), acc[it][3]);
        acc[it][4] = fmaf(v1, __uint_as_float(sv1.z << 16), acc[it][4]);
        acc[it][5] = fmaf(v1, __uint_as_float(sv1.z & 0xffff0000u), acc[it][5]);
        acc[it][6] = fmaf(v1, __uint_as_float(sv1.w << 16), acc[it][6]);
        acc[it][7] = fmaf(v1, __uint_as_float(sv1.w & 0xffff0000u), acc[it][7]);
        acc[it][0] = fmaf(v2, __uint_as_float(sv2.x << 16), acc[it][0]);
        acc[it][1] = fmaf(v2, __uint_as_float(sv2.x & 0xffff0000u), acc[it][1]);
        acc[it][2] = fmaf(v2, __uint_as_float(sv2.y << 16), acc[it][2]);
        acc[it][3] = fmaf(v2, __uint_as_float(sv2.y & 0xffff0000u), acc[it][3]);
        acc[it][4] = fmaf(v2, __uint_as_float(sv2.z << 16), acc[it][4]);
        acc[it][5] = fmaf(v2, __uint_as_float(sv2.z & 0xffff0000u), acc[it][5]);
        acc[it][6] = fmaf(v2, __uint_as_float(sv2.w << 16), acc[it][6]);
        acc[it][7] = fmaf(v2, __uint_as_float(sv2.w & 0xffff0000u), acc[it][7]);
        acc[it][0] = fmaf(v3, __uint_as_float(sv3.x << 16), acc[it][0]);
        acc[it][1] = fmaf(v3, __uint_as_float(sv3.x & 0xffff0000u), acc[it][1]);
        acc[it][2] = fmaf(v3, __uint_as_float(sv3.y << 16), acc[it][2]);
        acc[it][3] = fmaf(v3, __uint_as_float(sv3.y & 0xffff0000u), acc[it][3]);
        acc[it][4] = fmaf(v3, __uint_as_float(sv3.z << 16), acc[it][4]);
        acc[it][5] = fmaf(v3, __uint_as_float(sv3.z & 0xffff0000u), acc[it][5]);
        acc[it][6] = fmaf(v3, __uint_as_float(sv3.w << 16), acc[it][6]);
        acc[it][7] = fmaf(v3, __uint_as_float(sv3.w & 0xffff0000u), acc[it][7]);
      }
      for (; j < je; ++j) {
        uint2 e = ebuf[j];
        uint4 sv = *(const uint4*)&sup[(size_t)e.x * 64 + hl * 4];
        float v = __uint_as_float(e.y);
        acc[it][0] = fmaf(v, __uint_as_float(sv.x << 16), acc[it][0]);
        acc[it][1] = fmaf(v, __uint_as_float(sv.x & 0xffff0000u), acc[it][1]);
        acc[it][2] = fmaf(v, __uint_as_float(sv.y << 16), acc[it][2]);
        acc[it][3] = fmaf(v, __uint_as_float(sv.y & 0xffff0000u), acc[it][3]);
        acc[it][4] = fmaf(v, __uint_as_float(sv.z << 16), acc[it][4]);
        acc[it][5] = fmaf(v, __uint_as_float(sv.z & 0xffff0000u), acc[it][5]);
        acc[it][6] = fmaf(v, __uint_as_float(sv.w << 16), acc[it][6]);
        acc[it][7] = fmaf(v, __uint_as_float(sv.w & 0xffff0000u), acc[it][7]);
      }
    }
  }

  // Epilogue: out = acc + bias (coalesced per quarter)
  float4 b0 = *(const float4*)&bias[hl * 8];
  float4 b1 = *(const float4*)&bias[hl * 8 + 4];
#pragma unroll
  for (int it = 0; it < 4; ++it) {
    const int rid = it * 16 + wid * 4 + qtr;
    const int row = b * RPB + rid;
    if (row < n_nodes) {
      *(float4*)&out[(size_t)row * D + hl * 8] =
          make_float4(acc[it][0] + b0.x, acc[it][1] + b0.y,
                      acc[it][2] + b0.z, acc[it][3] + b0.w);
      *(float4*)&out[(size_t)row * D + hl * 8 + 4] =
          make_float4(acc[it][4] + b1.x, acc[it][5] + b1.y,
                      acc[it][6] + b1.z, acc[it][7] + b1.w);
    }
  }
}

extern "C" void kernel_launch(void* const* d_in, const int* in_sizes, int n_in,
                              void* d_out, int out_size, void* d_ws, size_t ws_size,
                              hipStream_t stream) {
  const float* x       = (const float*)d_in[0];
  const float* w       = (const float*)d_in[1];
  const float* bias    = (const float*)d_in[2];
  const int*   adj_row = (const int*)d_in[3];
  const int*   adj_col = (const int*)d_in[4];
  const float* adj_val = (const float*)d_in[5];

  const int n_nodes = in_sizes[0] / D;   // 50000
  const int n_edges = in_sizes[3];       // 800000
  float* out = (float*)d_out;

  const int nb = (n_nodes + RPB - 1) / RPB;        // 782  (<=1024)
  const int nc = (n_edges + CHUNK - 1) / CHUNK;    // 391  (<=512)
  const int gemm_blocks = (n_nodes + 63) / 64;     // 782

  // Workspace layout (16B-aligned). All buffers fully rewritten each
  // iteration -> NO memset needed (poison-safe).
  char* ws = (char*)d_ws;
  ushort* support  = (ushort*)ws; ws += ((size_t)n_nodes * D * 2 + 15) & ~15ull;  // 12.8 MB
  int*    counts   = (int*)ws;    ws += ((size_t)nb * nc * 4 + 15) & ~15ull;      // 1.22 MB
  int*    tot      = (int*)ws;    ws += ((size_t)nb * 4 + 15) & ~15ull;           // 3.1 KB
  int*    binStart = (int*)ws;    ws += ((size_t)(nb + 1) * 4 + 15) & ~15ull;     // 3.1 KB
  uint2*  sorted   = (uint2*)ws;  ws += (size_t)n_edges * 8;                      // 6.4 MB

  // 1) GEMM (782 blocks) || per-chunk histogram (391 blocks)
  gemm_hist_kernel<<<gemm_blocks + nc, 256, 0, stream>>>(
      x, w, support, n_nodes, gemm_blocks, adj_row, counts, n_edges, nb, nc);

  // 2) per-bin exclusive scan over chunks (in place) + totals
  scan_chunks_kernel<<<nb, 256, 0, stream>>>(counts, tot, nb, nc);

  // 3) exclusive scan over bins
  scan_bins_kernel<<<1, 256, 0, stream>>>(tot, binStart, nb);

  // 4) deterministic bin-sort of edges (no global atomics)
  sort_scatter_kernel<<<nc, 256, 0, stream>>>(adj_row, adj_col, adj_val,
                                              counts, binStart, sorted,
                                              n_edges, nb, nc);

  // 5) per-bin SpMM: out = bias + A @ support
  bin_spmm_kernel<<<nb, 256, 0, stream>>>(sorted, binStart, (const uint*)support,
                                          bias, out, n_nodes);
}

// Round 6
// 144.794 us; speedup vs baseline: 5.4625x; 1.0113x over previous
//
#include <hip/hip_runtime.h>

#define D 128
#define RPB 64        // rows per bin (power of 2)
#define RPB_SHIFT 6
#define EPT 8         // edges per thread in histogram/sort
#define CHUNK (256 * EPT)  // 2048 edges per chunk-block
#define PASS_EDGES 1280    // edges per bin_spmm pass (bin ~Poisson(1023); multi-pass fallback correct)

typedef __attribute__((ext_vector_type(8))) short short8;
typedef __attribute__((ext_vector_type(4))) float floatx4;
typedef __attribute__((ext_vector_type(4))) float f32x4;
typedef __attribute__((ext_vector_type(2))) unsigned int u32x2;
typedef unsigned int uint;
typedef unsigned short ushort;

__device__ inline short f2bf(float f) {
  unsigned u = __float_as_uint(f);
  u += 0x7FFF + ((u >> 16) & 1);  // RNE
  return (short)(u >> 16);
}

// --- Kernel A. Blocks [0, gemm_blocks): MFMA GEMM support = bf16(x @ W)
// (r0 code verbatim). Blocks [gemm_blocks, +nc): per-chunk row-bin histogram
// (LDS int atomics only -> counts[bin][chunk]). Co-scheduled (m114).
// r13: counting sort replaced 800K device-scope atomics (proven limiter).
__global__ __launch_bounds__(256) void gemm_hist_kernel(
    const float* __restrict__ x, const float* __restrict__ w,
    ushort* __restrict__ support, int n_nodes, int gemm_blocks,
    const int* __restrict__ adj_row, int* __restrict__ counts,
    int n_edges, int nb, int nc) {
  __shared__ short sWA[2 * 8 * 64 * 8];  // 16 KB (GEMM W tiles)
  __shared__ int hist[1024];             // histogram branch (nb <= 1024)
  const int tid = threadIdx.x;

  if ((int)blockIdx.x < gemm_blocks) {
    // ---------------- GEMM branch (r0 verbatim) ----------------
    const int wid = tid >> 6;
    const int lane = tid & 63;
    const int quad = lane >> 4;
    const int node = blockIdx.x * 64 + wid * 16 + (lane & 15);
    const bool ok = (node < n_nodes);

    floatx4 acc[8];
#pragma unroll
    for (int mt = 0; mt < 8; ++mt) acc[mt] = (floatx4){0.f, 0.f, 0.f, 0.f};

#pragma unroll
    for (int kt2 = 0; kt2 < 4; kt2 += 2) {
      if (kt2) __syncthreads();  // drain readers before restaging
      // Conflict-free staging (r8: 6M -> 0 conflicts).
      for (int s = tid; s < 1024; s += 256) {
        int ktmt = s >> 6, ls = s & 63;
        int kt = kt2 + (ktmt >> 3);
        int kb = kt * 32 + (ls >> 4) * 8;
        int m = (ktmt & 7) * 16 + (ls & 15);
        short8 frag;
#pragma unroll
        for (int j = 0; j < 8; ++j) frag[j] = f2bf(w[(kb + j) * D + m]);
        *(short8*)&sWA[s * 8] = frag;
      }
      __syncthreads();

#pragma unroll
      for (int ktoff = 0; ktoff < 2; ++ktoff) {
        const int kt = kt2 + ktoff;
        short8 bfr = (short8){0, 0, 0, 0, 0, 0, 0, 0};
        if (ok) {
          const float4 v0 = *(const float4*)&x[(size_t)node * D + kt * 32 + quad * 8];
          const float4 v1 = *(const float4*)&x[(size_t)node * D + kt * 32 + quad * 8 + 4];
          bfr = (short8){f2bf(v0.x), f2bf(v0.y), f2bf(v0.z), f2bf(v0.w),
                         f2bf(v1.x), f2bf(v1.y), f2bf(v1.z), f2bf(v1.w)};
        }
#pragma unroll
        for (int mt = 0; mt < 8; ++mt) {
          short8 a = *(const short8*)&sWA[((ktoff * 8 + mt) * 64 + lane) * 8];
          acc[mt] = __builtin_amdgcn_mfma_f32_16x16x32_bf16(a, bfr, acc[mt], 0, 0, 0);
        }
      }
    }

    if (ok) {
#pragma unroll
      for (int mt = 0; mt < 8; ++mt) {
        uint lo = ((uint)(ushort)f2bf(acc[mt][1]) << 16) | (ushort)f2bf(acc[mt][0]);
        uint hi = ((uint)(ushort)f2bf(acc[mt][3]) << 16) | (ushort)f2bf(acc[mt][2]);
        *(uint2*)&support[(size_t)node * D + mt * 16 + quad * 4] = make_uint2(lo, hi);
      }
    }
  } else {
    // ---------------- histogram branch ----------------
    const int c = blockIdx.x - gemm_blocks;
    for (int i = tid; i < nb; i += 256) hist[i] = 0;
    __syncthreads();
    const int base = c * CHUNK + tid * EPT;
    if (base + EPT <= n_edges) {
      int4 r0 = *(const int4*)&adj_row[base];
      int4 r1 = *(const int4*)&adj_row[base + 4];
      int rr[EPT] = {r0.x, r0.y, r0.z, r0.w, r1.x, r1.y, r1.z, r1.w};
#pragma unroll
      for (int u = 0; u < EPT; ++u) atomicAdd(&hist[rr[u] >> RPB_SHIFT], 1);
    } else {
      for (int u = 0; u < EPT; ++u) {
        int e = base + u;
        if (e < n_edges) atomicAdd(&hist[adj_row[e] >> RPB_SHIFT], 1);
      }
    }
    __syncthreads();
    for (int b = tid; b < nb; b += 256)
      counts[(size_t)b * nc + c] = hist[b];
  }
}

// --- Per-bin exclusive scan over chunks (in place) + bin totals.
__global__ __launch_bounds__(256) void scan_chunks_kernel(int* __restrict__ counts,
                                                          int* __restrict__ tot,
                                                          int nb, int nc) {
  __shared__ int buf[512];
  const int b = blockIdx.x;
  const int t = threadIdx.x;
  int v0 = (t < nc) ? counts[(size_t)b * nc + t] : 0;
  int v1 = (256 + t < nc) ? counts[(size_t)b * nc + 256 + t] : 0;
  buf[t] = v0;
  buf[256 + t] = v1;
  __syncthreads();
  for (int off = 1; off < 512; off <<= 1) {
    int a0 = buf[t], a1 = buf[256 + t];
    int d0 = (t >= off) ? buf[t - off] : 0;
    int d1 = (256 + t >= off) ? buf[256 + t - off] : 0;
    __syncthreads();
    buf[t] = a0 + d0;
    buf[256 + t] = a1 + d1;
    __syncthreads();
  }
  if (t < nc) counts[(size_t)b * nc + t] = buf[t] - v0;                // exclusive
  if (256 + t < nc) counts[(size_t)b * nc + 256 + t] = buf[256 + t] - v1;
  if (t == 0) tot[b] = buf[511];
}

// --- Exclusive scan over bin totals -> binStart[0..nb].
__global__ __launch_bounds__(256) void scan_bins_kernel(const int* __restrict__ tot,
                                                        int* __restrict__ binStart,
                                                        int nb) {
  __shared__ int buf[1024];
  const int t = threadIdx.x;
  for (int i = t; i < 1024; i += 256) buf[i] = (i < nb) ? tot[i] : 0;
  __syncthreads();
  for (int off = 1; off < 1024; off <<= 1) {
    int a[4], d[4];
#pragma unroll
    for (int k = 0; k < 4; ++k) {
      int i = t + 256 * k;
      a[k] = buf[i];
      d[k] = (i >= off) ? buf[i - off] : 0;
    }
    __syncthreads();
#pragma unroll
    for (int k = 0; k < 4; ++k) buf[t + 256 * k] = a[k] + d[k];
    __syncthreads();
  }
  for (int i = t; i < nb; i += 256) binStart[i] = buf[i] - tot[i];  // exclusive
  if (t == 0) binStart[nb] = buf[1023];
}

// --- Deterministic scatter into bin-sorted order (int LDS atomics only).
__global__ __launch_bounds__(256) void sort_scatter_kernel(
    const int* __restrict__ adj_row, const int* __restrict__ adj_col,
    const float* __restrict__ adj_val, const int* __restrict__ rel,
    const int* __restrict__ binStart, uint2* __restrict__ sorted,
    int n_edges, int nb, int nc) {
  __shared__ int loff[1024];
  const int c = blockIdx.x;
  const int t = threadIdx.x;
  for (int i = t; i < nb; i += 256)
    loff[i] = binStart[i] + rel[(size_t)i * nc + c];
  __syncthreads();

  const int base = c * CHUNK + t * EPT;
  if (base + EPT <= n_edges) {
    int4 r0 = *(const int4*)&adj_row[base];
    int4 r1 = *(const int4*)&adj_row[base + 4];
    int4 c0 = *(const int4*)&adj_col[base];
    int4 c1 = *(const int4*)&adj_col[base + 4];
    float4 v0 = *(const float4*)&adj_val[base];
    float4 v1 = *(const float4*)&adj_val[base + 4];
    int rr[EPT] = {r0.x, r0.y, r0.z, r0.w, r1.x, r1.y, r1.z, r1.w};
    int cc[EPT] = {c0.x, c0.y, c0.z, c0.w, c1.x, c1.y, c1.z, c1.w};
    float vv[EPT] = {v0.x, v0.y, v0.z, v0.w, v1.x, v1.y, v1.z, v1.w};
#pragma unroll
    for (int u = 0; u < EPT; ++u) {
      int r = rr[u];
      int pos = atomicAdd(&loff[r >> RPB_SHIFT], 1);  // int LDS atomic (native)
      sorted[pos] = make_uint2(((uint)(r & (RPB - 1)) << 16) | (uint)cc[u],
                               __float_as_uint(vv[u]));
    }
  } else {
    for (int u = 0; u < EPT; ++u) {
      int e = base + u;
      if (e >= n_edges) break;
      int r = adj_row[e];
      int pos = atomicAdd(&loff[r >> RPB_SHIFT], 1);
      sorted[pos] = make_uint2(((uint)(r & (RPB - 1)) << 16) | (uint)adj_col[e],
                               __float_as_uint(adj_val[e]));
    }
  }
}

#define FMA8(vv, sv, IT)                                                  \
  do {                                                                    \
    acc[IT][0] = fmaf(vv, __uint_as_float((sv).x << 16), acc[IT][0]);     \
    acc[IT][1] = fmaf(vv, __uint_as_float((sv).x & 0xffff0000u), acc[IT][1]); \
    acc[IT][2] = fmaf(vv, __uint_as_float((sv).y << 16), acc[IT][2]);     \
    acc[IT][3] = fmaf(vv, __uint_as_float((sv).y & 0xffff0000u), acc[IT][3]); \
    acc[IT][4] = fmaf(vv, __uint_as_float((sv).z << 16), acc[IT][4]);     \
    acc[IT][5] = fmaf(vv, __uint_as_float((sv).z & 0xffff0000u), acc[IT][5]); \
    acc[IT][6] = fmaf(vv, __uint_as_float((sv).w << 16), acc[IT][6]);     \
    acc[IT][7] = fmaf(vv, __uint_as_float((sv).w & 0xffff0000u), acc[IT][7]); \
  } while (0)

// --- Per-bin SpMM v3 (r15). v2 proven (790->146). r15: gather-latency is the
// limiter -> (a) unroll-8 consume: 8 dwordx4 gathers in flight per quarter
// (2x MLP); (b) PASS_EDGES 2048->1280: ebuf 16->10.2 KB, more blocks/CU to
// offset unroll VGPR growth; (c) nt on sorted loads (read-once, via ext-vector
// u32x2: builtin rejects HIP_vector_type) + out stores (full-line write-once)
// so L2 keeps the support gather set. No f32 atomics.
__global__ __launch_bounds__(256) void bin_spmm_kernel(
    const uint2* __restrict__ sorted, const int* __restrict__ binStart,
    const uint* __restrict__ sup, const float* __restrict__ bias,
    float* __restrict__ out, int n_nodes) {
  __shared__ uint2 ebuf[PASS_EDGES];   // 10.2 KB row-sorted edges
  __shared__ int rowStart[RPB + 1];
  __shared__ int cursor[RPB];          // hist, then running scatter cursor
  const int b = blockIdx.x;
  const int t = threadIdx.x;
  const int wid = t >> 6;
  const int lane = t & 63;
  const int qtr = lane >> 4;
  const int hl = lane & 15;

  const int s0 = binStart[b], s1 = binStart[b + 1];

  float acc[4][8];
#pragma unroll
  for (int it = 0; it < 4; ++it)
#pragma unroll
    for (int k = 0; k < 8; ++k) acc[it][k] = 0.f;

  for (int p0 = s0; p0 < s1; p0 += PASS_EDGES) {  // single pass in practice
    const int cntp = min(PASS_EDGES, s1 - p0);
    __syncthreads();                 // previous pass fully consumed
    if (t < RPB) cursor[t] = 0;
    __syncthreads();

    // Phase 1: load up to 8 edges into registers + row histogram (int atomics)
    u32x2 er[8];
    int rr[8];
    const int base = p0 + t * EPT;
#pragma unroll
    for (int u = 0; u < EPT; ++u) {
      if (t * EPT + u < cntp) {
        er[u] = __builtin_nontemporal_load(
            (const u32x2*)&sorted[base + u]);
        rr[u] = (int)(er[u][0] >> 16);
        atomicAdd(&cursor[rr[u]], 1);
      } else {
        er[u] = (u32x2){0u, 0u};
        rr[u] = -1;
      }
    }
    __syncthreads();

    // Phase 2: wave 0 scans the 64 row counts (exclusive)
    if (wid == 0) {
      int v = cursor[lane];
      int inc = v;
#pragma unroll
      for (int off = 1; off < 64; off <<= 1) {
        int u = __shfl_up(inc, off);
        if (lane >= off) inc += u;
      }
      rowStart[lane] = inc - v;
      if (lane == 63) rowStart[RPB] = inc;
    }
    __syncthreads();
    if (t < RPB) cursor[t] = rowStart[t];
    __syncthreads();

    // Phase 3: scatter edges into row-sorted LDS buffer
#pragma unroll
    for (int u = 0; u < EPT; ++u) {
      if (rr[u] >= 0) {
        int pos = atomicAdd(&cursor[rr[u]], 1);
        ebuf[pos] = make_uint2(er[u][0] & 0xFFFFu, er[u][1]);
      }
    }
    __syncthreads();

    // Phase 4: consume. 4 iters x 4 waves x 4 quarters = 64 rows. All 16
    // lanes of a quarter walk the row's segment together (LDS broadcast);
    // lane hl owns features [hl*8, hl*8+8). Register accumulation.
#pragma unroll
    for (int it = 0; it < 4; ++it) {
      const int rid = it * 16 + wid * 4 + qtr;
      const int js = rowStart[rid], je = rowStart[rid + 1];
      int j = js;
      for (; j + 8 <= je; j += 8) {   // 8 gathers in flight
        uint cols[8];
        float vs[8];
#pragma unroll
        for (int u = 0; u < 8; ++u) {
          uint2 e = ebuf[j + u];
          cols[u] = e.x;
          vs[u] = __uint_as_float(e.y);
        }
        uint4 sv[8];
#pragma unroll
        for (int u = 0; u < 8; ++u)
          sv[u] = *(const uint4*)&sup[(size_t)cols[u] * 64 + hl * 4];
#pragma unroll
        for (int u = 0; u < 8; ++u) FMA8(vs[u], sv[u], it);
      }
      for (; j + 4 <= je; j += 4) {
        uint cols[4];
        float vs[4];
#pragma unroll
        for (int u = 0; u < 4; ++u) {
          uint2 e = ebuf[j + u];
          cols[u] = e.x;
          vs[u] = __uint_as_float(e.y);
        }
        uint4 sv[4];
#pragma unroll
        for (int u = 0; u < 4; ++u)
          sv[u] = *(const uint4*)&sup[(size_t)cols[u] * 64 + hl * 4];
#pragma unroll
        for (int u = 0; u < 4; ++u) FMA8(vs[u], sv[u], it);
      }
      for (; j < je; ++j) {
        uint2 e = ebuf[j];
        uint4 sv = *(const uint4*)&sup[(size_t)e.x * 64 + hl * 4];
        float v = __uint_as_float(e.y);
        FMA8(v, sv, it);
      }
    }
  }

  // Epilogue: out = acc + bias (coalesced per quarter; nt: full-line
  // write-once stream, keep L2 for support gathers)
  float4 b0 = *(const float4*)&bias[hl * 8];
  float4 b1 = *(const float4*)&bias[hl * 8 + 4];
#pragma unroll
  for (int it = 0; it < 4; ++it) {
    const int rid = it * 16 + wid * 4 + qtr;
    const int row = b * RPB + rid;
    if (row < n_nodes) {
      f32x4 o0 = {acc[it][0] + b0.x, acc[it][1] + b0.y,
                  acc[it][2] + b0.z, acc[it][3] + b0.w};
      f32x4 o1 = {acc[it][4] + b1.x, acc[it][5] + b1.y,
                  acc[it][6] + b1.z, acc[it][7] + b1.w};
      __builtin_nontemporal_store(o0, (f32x4*)&out[(size_t)row * D + hl * 8]);
      __builtin_nontemporal_store(o1, (f32x4*)&out[(size_t)row * D + hl * 8 + 4]);
    }
  }
}

extern "C" void kernel_launch(void* const* d_in, const int* in_sizes, int n_in,
                              void* d_out, int out_size, void* d_ws, size_t ws_size,
                              hipStream_t stream) {
  const float* x       = (const float*)d_in[0];
  const float* w       = (const float*)d_in[1];
  const float* bias    = (const float*)d_in[2];
  const int*   adj_row = (const int*)d_in[3];
  const int*   adj_col = (const int*)d_in[4];
  const float* adj_val = (const float*)d_in[5];

  const int n_nodes = in_sizes[0] / D;   // 50000
  const int n_edges = in_sizes[3];       // 800000
  float* out = (float*)d_out;

  const int nb = (n_nodes + RPB - 1) / RPB;        // 782  (<=1024)
  const int nc = (n_edges + CHUNK - 1) / CHUNK;    // 391  (<=512)
  const int gemm_blocks = (n_nodes + 63) / 64;     // 782

  // Workspace layout (16B-aligned). All buffers fully rewritten each
  // iteration -> NO memset needed (poison-safe).
  char* ws = (char*)d_ws;
  ushort* support  = (ushort*)ws; ws += ((size_t)n_nodes * D * 2 + 15) & ~15ull;  // 12.8 MB
  int*    counts   = (int*)ws;    ws += ((size_t)nb * nc * 4 + 15) & ~15ull;      // 1.22 MB
  int*    tot      = (int*)ws;    ws += ((size_t)nb * 4 + 15) & ~15ull;           // 3.1 KB
  int*    binStart = (int*)ws;    ws += ((size_t)(nb + 1) * 4 + 15) & ~15ull;     // 3.1 KB
  uint2*  sorted   = (uint2*)ws;  ws += (size_t)n_edges * 8;                      // 6.4 MB

  // 1) GEMM (782 blocks) || per-chunk histogram (391 blocks)
  gemm_hist_kernel<<<gemm_blocks + nc, 256, 0, stream>>>(
      x, w, support, n_nodes, gemm_blocks, adj_row, counts, n_edges, nb, nc);

  // 2) per-bin exclusive scan over chunks (in place) + totals
  scan_chunks_kernel<<<nb, 256, 0, stream>>>(counts, tot, nb, nc);

  // 3) exclusive scan over bins
  scan_bins_kernel<<<1, 256, 0, stream>>>(tot, binStart, nb);

  // 4) deterministic bin-sort of edges (no global atomics)
  sort_scatter_kernel<<<nc, 256, 0, stream>>>(adj_row, adj_col, adj_val,
                                              counts, binStart, sorted,
                                              n_edges, nb, nc);

  // 5) per-bin SpMM: out = bias + A @ support
  bin_spmm_kernel<<<nb, 256, 0, stream>>>(sorted, binStart, (const uint*)support,
                                          bias, out, n_nodes);
}

// Round 7
// 142.381 us; speedup vs baseline: 5.5551x; 1.0169x over previous
//
#include <hip/hip_runtime.h>

#define D 128
#define RPB 64        // rows per bin (power of 2)
#define RPB_SHIFT 6
#define EPT 8         // edges per thread in histogram/sort
#define CHUNK (256 * EPT)  // 2048 edges per chunk-block
#define PASS_EDGES 1280    // edges per bin_spmm pass (bin ~Poisson(1023); multi-pass fallback correct)

typedef __attribute__((ext_vector_type(8))) short short8;
typedef __attribute__((ext_vector_type(4))) float floatx4;
typedef __attribute__((ext_vector_type(4))) float f32x4;
typedef __attribute__((ext_vector_type(2))) unsigned int u32x2;
typedef unsigned int uint;
typedef unsigned short ushort;

__device__ inline short f2bf(float f) {
  unsigned u = __float_as_uint(f);
  u += 0x7FFF + ((u >> 16) & 1);  // RNE
  return (short)(u >> 16);
}

// --- K1 (r16): histogram (blocks [0,nc)) || W->bf16 TRANSPOSED convert
// (blocks [nc, nc+8)). r16 THEORY: GEMM was serialized ahead of the scan/sort
// pipeline that doesn't need it; also each GEMM block re-converted the same
// 64KB W (782x redundant f2bf). Convert once to wt[m][k] (transposed) so GEMM
// staging is a contiguous 16B vector load.
__global__ __launch_bounds__(256) void hist_wconv_kernel(
    const int* __restrict__ adj_row, int* __restrict__ counts,
    int n_edges, int nb, int nc,
    const float* __restrict__ w, ushort* __restrict__ wt) {
  __shared__ int hist[1024];
  const int tid = threadIdx.x;

  if ((int)blockIdx.x < nc) {
    // ---------------- histogram branch ----------------
    const int c = blockIdx.x;
    for (int i = tid; i < nb; i += 256) hist[i] = 0;
    __syncthreads();
    const int base = c * CHUNK + tid * EPT;
    if (base + EPT <= n_edges) {
      int4 r0 = *(const int4*)&adj_row[base];
      int4 r1 = *(const int4*)&adj_row[base + 4];
      int rr[EPT] = {r0.x, r0.y, r0.z, r0.w, r1.x, r1.y, r1.z, r1.w};
#pragma unroll
      for (int u = 0; u < EPT; ++u) atomicAdd(&hist[rr[u] >> RPB_SHIFT], 1);
    } else {
      for (int u = 0; u < EPT; ++u) {
        int e = base + u;
        if (e < n_edges) atomicAdd(&hist[adj_row[e] >> RPB_SHIFT], 1);
      }
    }
    __syncthreads();
    for (int b = tid; b < nb; b += 256)
      counts[(size_t)b * nc + c] = hist[b];
  } else {
    // ---------------- W convert+transpose branch ----------------
    // wt[m][k] = bf16(w[k][m]); 8 blocks x 256 thr x 8 elems = 16384 = 128*128
    const int idx = ((int)blockIdx.x - nc) * 256 + tid;
    const int m = idx >> 4;
    const int ks = (idx & 15) * 8;
    short8 frag;
#pragma unroll
    for (int j = 0; j < 8; ++j) frag[j] = f2bf(w[(ks + j) * D + m]);
    *(short8*)&wt[(size_t)m * D + ks] = frag;
  }
}

// --- Per-bin exclusive scan over chunks (in place) + bin totals.
__global__ __launch_bounds__(256) void scan_chunks_kernel(int* __restrict__ counts,
                                                          int* __restrict__ tot,
                                                          int nb, int nc) {
  __shared__ int buf[512];
  const int b = blockIdx.x;
  const int t = threadIdx.x;
  int v0 = (t < nc) ? counts[(size_t)b * nc + t] : 0;
  int v1 = (256 + t < nc) ? counts[(size_t)b * nc + 256 + t] : 0;
  buf[t] = v0;
  buf[256 + t] = v1;
  __syncthreads();
  for (int off = 1; off < 512; off <<= 1) {
    int a0 = buf[t], a1 = buf[256 + t];
    int d0 = (t >= off) ? buf[t - off] : 0;
    int d1 = (256 + t >= off) ? buf[256 + t - off] : 0;
    __syncthreads();
    buf[t] = a0 + d0;
    buf[256 + t] = a1 + d1;
    __syncthreads();
  }
  if (t < nc) counts[(size_t)b * nc + t] = buf[t] - v0;                // exclusive
  if (256 + t < nc) counts[(size_t)b * nc + 256 + t] = buf[256 + t] - v1;
  if (t == 0) tot[b] = buf[511];
}

// --- Exclusive scan over bin totals -> binStart[0..nb].
__global__ __launch_bounds__(256) void scan_bins_kernel(const int* __restrict__ tot,
                                                        int* __restrict__ binStart,
                                                        int nb) {
  __shared__ int buf[1024];
  const int t = threadIdx.x;
  for (int i = t; i < 1024; i += 256) buf[i] = (i < nb) ? tot[i] : 0;
  __syncthreads();
  for (int off = 1; off < 1024; off <<= 1) {
    int a[4], d[4];
#pragma unroll
    for (int k = 0; k < 4; ++k) {
      int i = t + 256 * k;
      a[k] = buf[i];
      d[k] = (i >= off) ? buf[i - off] : 0;
    }
    __syncthreads();
#pragma unroll
    for (int k = 0; k < 4; ++k) buf[t + 256 * k] = a[k] + d[k];
    __syncthreads();
  }
  for (int i = t; i < nb; i += 256) binStart[i] = buf[i] - tot[i];  // exclusive
  if (t == 0) binStart[nb] = buf[1023];
}

// --- K4 (r16): MFMA GEMM support = bf16(x) @ bf16(W) (blocks [0,gemm_blocks),
// staging W from pre-converted TRANSPOSED wt -> one short8 load + ds_write_b128
// per fragment, zero f2bf for W) || deterministic bin-sort scatter (blocks
// [gemm_blocks, +nc)). The two long independent mid-stages overlap (m114);
// GEMM is off the scan pipeline's critical path.
__global__ __launch_bounds__(256) void gemm_sort_kernel(
    const float* __restrict__ x, const ushort* __restrict__ wt,
    ushort* __restrict__ support, int n_nodes, int gemm_blocks,
    const int* __restrict__ adj_row, const int* __restrict__ adj_col,
    const float* __restrict__ adj_val, const int* __restrict__ rel,
    const int* __restrict__ binStart, uint2* __restrict__ sorted,
    int n_edges, int nb, int nc) {
  __shared__ short sWA[2 * 8 * 64 * 8];  // 16 KB (GEMM W tiles / sort loff)
  const int tid = threadIdx.x;

  if ((int)blockIdx.x < gemm_blocks) {
    // ---------------- GEMM branch ----------------
    const int wid = tid >> 6;
    const int lane = tid & 63;
    const int quad = lane >> 4;
    const int node = blockIdx.x * 64 + wid * 16 + (lane & 15);
    const bool ok = (node < n_nodes);

    floatx4 acc[8];
#pragma unroll
    for (int mt = 0; mt < 8; ++mt) acc[mt] = (floatx4){0.f, 0.f, 0.f, 0.f};

#pragma unroll
    for (int kt2 = 0; kt2 < 4; kt2 += 2) {
      if (kt2) __syncthreads();  // drain readers before restaging
      // Staging from wt (conflict-free, r8): one short8 vector load (16B
      // contiguous: wt is transposed) -> one ds_write_b128 per fragment.
      for (int s = tid; s < 1024; s += 256) {
        int ktmt = s >> 6, ls = s & 63;
        int kt = kt2 + (ktmt >> 3);
        int kb = kt * 32 + (ls >> 4) * 8;     // k-base of fragment
        int m = (ktmt & 7) * 16 + (ls & 15);  // output feature
        *(short8*)&sWA[s * 8] = *(const short8*)&wt[(size_t)m * D + kb];
      }
      __syncthreads();

#pragma unroll
      for (int ktoff = 0; ktoff < 2; ++ktoff) {
        const int kt = kt2 + ktoff;
        short8 bfr = (short8){0, 0, 0, 0, 0, 0, 0, 0};
        if (ok) {
          const float4 v0 = *(const float4*)&x[(size_t)node * D + kt * 32 + quad * 8];
          const float4 v1 = *(const float4*)&x[(size_t)node * D + kt * 32 + quad * 8 + 4];
          bfr = (short8){f2bf(v0.x), f2bf(v0.y), f2bf(v0.z), f2bf(v0.w),
                         f2bf(v1.x), f2bf(v1.y), f2bf(v1.z), f2bf(v1.w)};
        }
#pragma unroll
        for (int mt = 0; mt < 8; ++mt) {
          short8 a = *(const short8*)&sWA[((ktoff * 8 + mt) * 64 + lane) * 8];
          acc[mt] = __builtin_amdgcn_mfma_f32_16x16x32_bf16(a, bfr, acc[mt], 0, 0, 0);
        }
      }
    }

    if (ok) {
#pragma unroll
      for (int mt = 0; mt < 8; ++mt) {
        uint lo = ((uint)(ushort)f2bf(acc[mt][1]) << 16) | (ushort)f2bf(acc[mt][0]);
        uint hi = ((uint)(ushort)f2bf(acc[mt][3]) << 16) | (ushort)f2bf(acc[mt][2]);
        *(uint2*)&support[(size_t)node * D + mt * 16 + quad * 4] = make_uint2(lo, hi);
      }
    }
  } else {
    // ---------------- sort_scatter branch (int LDS atomics only) ----------------
    int* loff = (int*)sWA;  // 4KB of the 16KB
    const int c = (int)blockIdx.x - gemm_blocks;
    for (int i = tid; i < nb; i += 256)
      loff[i] = binStart[i] + rel[(size_t)i * nc + c];
    __syncthreads();

    const int base = c * CHUNK + tid * EPT;
    if (base + EPT <= n_edges) {
      int4 r0 = *(const int4*)&adj_row[base];
      int4 r1 = *(const int4*)&adj_row[base + 4];
      int4 c0 = *(const int4*)&adj_col[base];
      int4 c1 = *(const int4*)&adj_col[base + 4];
      float4 v0 = *(const float4*)&adj_val[base];
      float4 v1 = *(const float4*)&adj_val[base + 4];
      int rr[EPT] = {r0.x, r0.y, r0.z, r0.w, r1.x, r1.y, r1.z, r1.w};
      int cc[EPT] = {c0.x, c0.y, c0.z, c0.w, c1.x, c1.y, c1.z, c1.w};
      float vv[EPT] = {v0.x, v0.y, v0.z, v0.w, v1.x, v1.y, v1.z, v1.w};
#pragma unroll
      for (int u = 0; u < EPT; ++u) {
        int r = rr[u];
        int pos = atomicAdd(&loff[r >> RPB_SHIFT], 1);  // int LDS atomic (native)
        sorted[pos] = make_uint2(((uint)(r & (RPB - 1)) << 16) | (uint)cc[u],
                                 __float_as_uint(vv[u]));
      }
    } else {
      for (int u = 0; u < EPT; ++u) {
        int e = base + u;
        if (e >= n_edges) break;
        int r = adj_row[e];
        int pos = atomicAdd(&loff[r >> RPB_SHIFT], 1);
        sorted[pos] = make_uint2(((uint)(r & (RPB - 1)) << 16) | (uint)adj_col[e],
                                 __float_as_uint(adj_val[e]));
      }
    }
  }
}

#define FMA8(vv, sv, IT)                                                  \
  do {                                                                    \
    acc[IT][0] = fmaf(vv, __uint_as_float((sv).x << 16), acc[IT][0]);     \
    acc[IT][1] = fmaf(vv, __uint_as_float((sv).x & 0xffff0000u), acc[IT][1]); \
    acc[IT][2] = fmaf(vv, __uint_as_float((sv).y << 16), acc[IT][2]);     \
    acc[IT][3] = fmaf(vv, __uint_as_float((sv).y & 0xffff0000u), acc[IT][3]); \
    acc[IT][4] = fmaf(vv, __uint_as_float((sv).z << 16), acc[IT][4]);     \
    acc[IT][5] = fmaf(vv, __uint_as_float((sv).z & 0xffff0000u), acc[IT][5]); \
    acc[IT][6] = fmaf(vv, __uint_as_float((sv).w << 16), acc[IT][6]);     \
    acc[IT][7] = fmaf(vv, __uint_as_float((sv).w & 0xffff0000u), acc[IT][7]); \
  } while (0)

// --- Per-bin SpMM (r15 verbatim: proven). In-LDS row counting sort (int
// atomics) then 16-lanes-per-row register-accum consume, unroll-8 MLP,
// nt on read-once sorted loads + write-once out stores.
__global__ __launch_bounds__(256) void bin_spmm_kernel(
    const uint2* __restrict__ sorted, const int* __restrict__ binStart,
    const uint* __restrict__ sup, const float* __restrict__ bias,
    float* __restrict__ out, int n_nodes) {
  __shared__ uint2 ebuf[PASS_EDGES];   // 10.2 KB row-sorted edges
  __shared__ int rowStart[RPB + 1];
  __shared__ int cursor[RPB];          // hist, then running scatter cursor
  const int b = blockIdx.x;
  const int t = threadIdx.x;
  const int wid = t >> 6;
  const int lane = t & 63;
  const int qtr = lane >> 4;
  const int hl = lane & 15;

  const int s0 = binStart[b], s1 = binStart[b + 1];

  float acc[4][8];
#pragma unroll
  for (int it = 0; it < 4; ++it)
#pragma unroll
    for (int k = 0; k < 8; ++k) acc[it][k] = 0.f;

  for (int p0 = s0; p0 < s1; p0 += PASS_EDGES) {  // single pass in practice
    const int cntp = min(PASS_EDGES, s1 - p0);
    __syncthreads();                 // previous pass fully consumed
    if (t < RPB) cursor[t] = 0;
    __syncthreads();

    // Phase 1: load up to 8 edges into registers + row histogram (int atomics)
    u32x2 er[8];
    int rr[8];
    const int base = p0 + t * EPT;
#pragma unroll
    for (int u = 0; u < EPT; ++u) {
      if (t * EPT + u < cntp) {
        er[u] = __builtin_nontemporal_load(
            (const u32x2*)&sorted[base + u]);
        rr[u] = (int)(er[u][0] >> 16);
        atomicAdd(&cursor[rr[u]], 1);
      } else {
        er[u] = (u32x2){0u, 0u};
        rr[u] = -1;
      }
    }
    __syncthreads();

    // Phase 2: wave 0 scans the 64 row counts (exclusive)
    if (wid == 0) {
      int v = cursor[lane];
      int inc = v;
#pragma unroll
      for (int off = 1; off < 64; off <<= 1) {
        int u = __shfl_up(inc, off);
        if (lane >= off) inc += u;
      }
      rowStart[lane] = inc - v;
      if (lane == 63) rowStart[RPB] = inc;
    }
    __syncthreads();
    if (t < RPB) cursor[t] = rowStart[t];
    __syncthreads();

    // Phase 3: scatter edges into row-sorted LDS buffer
#pragma unroll
    for (int u = 0; u < EPT; ++u) {
      if (rr[u] >= 0) {
        int pos = atomicAdd(&cursor[rr[u]], 1);
        ebuf[pos] = make_uint2(er[u][0] & 0xFFFFu, er[u][1]);
      }
    }
    __syncthreads();

    // Phase 4: consume. 4 iters x 4 waves x 4 quarters = 64 rows. All 16
    // lanes of a quarter walk the row's segment together (LDS broadcast);
    // lane hl owns features [hl*8, hl*8+8). Register accumulation.
#pragma unroll
    for (int it = 0; it < 4; ++it) {
      const int rid = it * 16 + wid * 4 + qtr;
      const int js = rowStart[rid], je = rowStart[rid + 1];
      int j = js;
      for (; j + 8 <= je; j += 8) {   // 8 gathers in flight
        uint cols[8];
        float vs[8];
#pragma unroll
        for (int u = 0; u < 8; ++u) {
          uint2 e = ebuf[j + u];
          cols[u] = e.x;
          vs[u] = __uint_as_float(e.y);
        }
        uint4 sv[8];
#pragma unroll
        for (int u = 0; u < 8; ++u)
          sv[u] = *(const uint4*)&sup[(size_t)cols[u] * 64 + hl * 4];
#pragma unroll
        for (int u = 0; u < 8; ++u) FMA8(vs[u], sv[u], it);
      }
      for (; j + 4 <= je; j += 4) {
        uint cols[4];
        float vs[4];
#pragma unroll
        for (int u = 0; u < 4; ++u) {
          uint2 e = ebuf[j + u];
          cols[u] = e.x;
          vs[u] = __uint_as_float(e.y);
        }
        uint4 sv[4];
#pragma unroll
        for (int u = 0; u < 4; ++u)
          sv[u] = *(const uint4*)&sup[(size_t)cols[u] * 64 + hl * 4];
#pragma unroll
        for (int u = 0; u < 4; ++u) FMA8(vs[u], sv[u], it);
      }
      for (; j < je; ++j) {
        uint2 e = ebuf[j];
        uint4 sv = *(const uint4*)&sup[(size_t)e.x * 64 + hl * 4];
        float v = __uint_as_float(e.y);
        FMA8(v, sv, it);
      }
    }
  }

  // Epilogue: out = acc + bias (coalesced per quarter; nt: full-line
  // write-once stream, keep L2 for support gathers)
  float4 b0 = *(const float4*)&bias[hl * 8];
  float4 b1 = *(const float4*)&bias[hl * 8 + 4];
#pragma unroll
  for (int it = 0; it < 4; ++it) {
    const int rid = it * 16 + wid * 4 + qtr;
    const int row = b * RPB + rid;
    if (row < n_nodes) {
      f32x4 o0 = {acc[it][0] + b0.x, acc[it][1] + b0.y,
                  acc[it][2] + b0.z, acc[it][3] + b0.w};
      f32x4 o1 = {acc[it][4] + b1.x, acc[it][5] + b1.y,
                  acc[it][6] + b1.z, acc[it][7] + b1.w};
      __builtin_nontemporal_store(o0, (f32x4*)&out[(size_t)row * D + hl * 8]);
      __builtin_nontemporal_store(o1, (f32x4*)&out[(size_t)row * D + hl * 8 + 4]);
    }
  }
}

extern "C" void kernel_launch(void* const* d_in, const int* in_sizes, int n_in,
                              void* d_out, int out_size, void* d_ws, size_t ws_size,
                              hipStream_t stream) {
  const float* x       = (const float*)d_in[0];
  const float* w       = (const float*)d_in[1];
  const float* bias    = (const float*)d_in[2];
  const int*   adj_row = (const int*)d_in[3];
  const int*   adj_col = (const int*)d_in[4];
  const float* adj_val = (const float*)d_in[5];

  const int n_nodes = in_sizes[0] / D;   // 50000
  const int n_edges = in_sizes[3];       // 800000
  float* out = (float*)d_out;

  const int nb = (n_nodes + RPB - 1) / RPB;        // 782  (<=1024)
  const int nc = (n_edges + CHUNK - 1) / CHUNK;    // 391  (<=512)
  const int gemm_blocks = (n_nodes + 63) / 64;     // 782

  // Workspace layout (16B-aligned). All buffers fully rewritten each
  // iteration -> NO memset needed (poison-safe).
  char* ws = (char*)d_ws;
  ushort* support  = (ushort*)ws; ws += ((size_t)n_nodes * D * 2 + 15) & ~15ull;  // 12.8 MB
  int*    counts   = (int*)ws;    ws += ((size_t)nb * nc * 4 + 15) & ~15ull;      // 1.22 MB
  int*    tot      = (int*)ws;    ws += ((size_t)nb * 4 + 15) & ~15ull;           // 3.1 KB
  int*    binStart = (int*)ws;    ws += ((size_t)(nb + 1) * 4 + 15) & ~15ull;     // 3.1 KB
  ushort* wt       = (ushort*)ws; ws += (size_t)D * D * 2;                        // 32 KB
  uint2*  sorted   = (uint2*)ws;  ws += (size_t)n_edges * 8;                      // 6.4 MB

  // 1) histogram (391 blocks) || W->bf16^T convert (8 blocks)
  hist_wconv_kernel<<<nc + 8, 256, 0, stream>>>(adj_row, counts, n_edges, nb, nc,
                                                w, wt);

  // 2) per-bin exclusive scan over chunks (in place) + totals
  scan_chunks_kernel<<<nb, 256, 0, stream>>>(counts, tot, nb, nc);

  // 3) exclusive scan over bins
  scan_bins_kernel<<<1, 256, 0, stream>>>(tot, binStart, nb);

  // 4) GEMM (782 blocks) || deterministic bin-sort (391 blocks)
  gemm_sort_kernel<<<gemm_blocks + nc, 256, 0, stream>>>(
      x, wt, support, n_nodes, gemm_blocks,
      adj_row, adj_col, adj_val, counts, binStart, sorted, n_edges, nb, nc);

  // 5) per-bin SpMM: out = bias + A @ support
  bin_spmm_kernel<<<nb, 256, 0, stream>>>(sorted, binStart, (const uint*)support,
                                          bias, out, n_nodes);
}